// Round 6
// baseline (294.698 us; speedup 1.0000x reference)
//
#include <hip/hip_runtime.h>
#include <hip/hip_bf16.h>
#include <hip/hip_cooperative_groups.h>

namespace cg = cooperative_groups;

#define N_NODES 10000
#define N_EDGES 320000
#define D 256        // D_IN == D_OUT
#define K_TOT 512    // 2*D
#define CAP 128      // per-node bucket capacity (max Poisson(32) degree ~65)

#define GRID_BLKS 628          // == number of 64x64 GEMM tiles (157*4)
#define NTHREADS (GRID_BLKS * 256)

typedef __attribute__((ext_vector_type(8))) short bf16x8;
typedef __attribute__((ext_vector_type(4))) float f32x4;

__device__ __forceinline__ float bf2f(unsigned short u) {
  return __uint_as_float(((unsigned int)u) << 16);
}
__device__ __forceinline__ unsigned short f2bf(float f) {
  unsigned int x = __float_as_uint(f);
  unsigned int r = (x + 0x7fffu + ((x >> 16) & 1u)) >> 16;   // RNE
  return (unsigned short)r;
}

#define FEAT_VECS (N_NODES * D / 8)     // 320000
#define W_VECS    (D * K_TOT / 8)       // 16384
#define CUR_VECS  (N_NODES / 4)         // 2500 (int4 zeroing)
#define P0_TOT    (FEAT_VECS + W_VECS + CUR_VECS)

#define GBM 64
#define GBN 64
#define GBK 64
#define LPAD 72   // LDS row stride in bf16 elems (+8 pad: 2-way bank alias, free)
#define MTILES 157  // ceil(10000/64)

// ---------------------------------------------------------------------------
// Single cooperative kernel: convert+zero | append | agg | gemm, separated by
// grid.sync(). Replaces 4 dispatches (saves launch gaps + fixes GEMM tail:
// 628 blocks == 628 tiles, one tile per block).
// ---------------------------------------------------------------------------
__global__ __launch_bounds__(256, 3) void fused_kernel(
    const float* __restrict__ feat, const float* __restrict__ ew,
    const float* __restrict__ W, const float* __restrict__ bias,
    const int* __restrict__ src, const int* __restrict__ dst,
    unsigned short* __restrict__ hcat, unsigned short* __restrict__ Wb,
    int* __restrict__ cursor, int2* __restrict__ bucket,
    float* __restrict__ out) {
  __shared__ unsigned short As[GBM][LPAD];  // 9.2 KB
  __shared__ unsigned short Bs[GBN][LPAD];  // 9.2 KB

  cg::grid_group grid = cg::this_grid();
  const int tid = blockIdx.x * 256 + threadIdx.x;

  // ---------------- Phase 0: feat->bf16, W->bf16, zero cursor ----------------
  for (int gid = tid; gid < P0_TOT; gid += NTHREADS) {
    if (gid < FEAT_VECS) {
      int row = gid >> 5;          // 32 vec8 per 256-row
      int v = gid & 31;
      const float* srcp = feat + (size_t)row * D + v * 8;
      unsigned short* dstp = hcat + (size_t)row * K_TOT + D + v * 8;
      float4 a = reinterpret_cast<const float4*>(srcp)[0];
      float4 b = reinterpret_cast<const float4*>(srcp)[1];
      reinterpret_cast<ushort4*>(dstp)[0] =
          make_ushort4(f2bf(a.x), f2bf(a.y), f2bf(a.z), f2bf(a.w));
      reinterpret_cast<ushort4*>(dstp)[1] =
          make_ushort4(f2bf(b.x), f2bf(b.y), f2bf(b.z), f2bf(b.w));
    } else if (gid < FEAT_VECS + W_VECS) {
      int g = gid - FEAT_VECS;
      int row = g >> 6;            // 64 vec8 per 512-row
      int v = g & 63;
      const float* srcp = W + (size_t)row * K_TOT + v * 8;
      unsigned short* dstp = Wb + (size_t)row * K_TOT + v * 8;
      float4 a = reinterpret_cast<const float4*>(srcp)[0];
      float4 b = reinterpret_cast<const float4*>(srcp)[1];
      reinterpret_cast<ushort4*>(dstp)[0] =
          make_ushort4(f2bf(a.x), f2bf(a.y), f2bf(a.z), f2bf(a.w));
      reinterpret_cast<ushort4*>(dstp)[1] =
          make_ushort4(f2bf(b.x), f2bf(b.y), f2bf(b.z), f2bf(b.w));
    } else {
      int g = gid - (FEAT_VECS + W_VECS);
      reinterpret_cast<int4*>(cursor)[g] = make_int4(0, 0, 0, 0);
    }
  }
  grid.sync();

  // ---------------- Phase 1: atomic-append edges into per-dst buckets -------
  for (int i = tid; i < N_EDGES; i += NTHREADS) {
    int d = dst[i];
    int pos = atomicAdd(&cursor[d], 1);
    if (pos < CAP)
      bucket[(size_t)d * CAP + pos] = make_int2(src[i], __float_as_int(ew[i]));
  }
  grid.sync();

  // ---------------- Phase 2: per-node mean aggregation (1 wave / node) ------
  {
    int wid = tid >> 6;
    int lane = tid & 63;
    const int NW = NTHREADS >> 6;   // 2512 waves
    for (int node = wid; node < N_NODES; node += NW) {
      int cnt = cursor[node];
      int end = min(cnt, CAP);
      const int2* bk = bucket + (size_t)node * CAP;
      float acc0 = 0.f, acc1 = 0.f, acc2 = 0.f, acc3 = 0.f;
      int i = 0;
      for (; i + 4 <= end; i += 4) {
        int4 e01 = *reinterpret_cast<const int4*>(bk + i);
        int4 e23 = *reinterpret_cast<const int4*>(bk + i + 2);
        ushort4 v0 = *reinterpret_cast<const ushort4*>(hcat + (size_t)e01.x * K_TOT + D + lane * 4);
        ushort4 v1 = *reinterpret_cast<const ushort4*>(hcat + (size_t)e01.z * K_TOT + D + lane * 4);
        ushort4 v2 = *reinterpret_cast<const ushort4*>(hcat + (size_t)e23.x * K_TOT + D + lane * 4);
        ushort4 v3 = *reinterpret_cast<const ushort4*>(hcat + (size_t)e23.z * K_TOT + D + lane * 4);
        float w0 = __int_as_float(e01.y), w1 = __int_as_float(e01.w);
        float w2 = __int_as_float(e23.y), w3 = __int_as_float(e23.w);
        acc0 += bf2f(v0.x) * w0; acc1 += bf2f(v0.y) * w0; acc2 += bf2f(v0.z) * w0; acc3 += bf2f(v0.w) * w0;
        acc0 += bf2f(v1.x) * w1; acc1 += bf2f(v1.y) * w1; acc2 += bf2f(v1.z) * w1; acc3 += bf2f(v1.w) * w1;
        acc0 += bf2f(v2.x) * w2; acc1 += bf2f(v2.y) * w2; acc2 += bf2f(v2.z) * w2; acc3 += bf2f(v2.w) * w2;
        acc0 += bf2f(v3.x) * w3; acc1 += bf2f(v3.y) * w3; acc2 += bf2f(v3.z) * w3; acc3 += bf2f(v3.w) * w3;
      }
      for (; i < end; ++i) {
        int2 sw = bk[i];
        ushort4 v = *reinterpret_cast<const ushort4*>(hcat + (size_t)sw.x * K_TOT + D + lane * 4);
        float w = __int_as_float(sw.y);
        acc0 += bf2f(v.x) * w; acc1 += bf2f(v.y) * w; acc2 += bf2f(v.z) * w; acc3 += bf2f(v.w) * w;
      }
      float inv = 1.0f / fmaxf((float)cnt, 1.0f);
      ushort4 o = make_ushort4(f2bf(acc0 * inv), f2bf(acc1 * inv),
                               f2bf(acc2 * inv), f2bf(acc3 * inv));
      *reinterpret_cast<ushort4*>(hcat + (size_t)node * K_TOT + lane * 4) = o;
    }
  }
  grid.sync();

  // ---------------- Phase 3: MFMA GEMM, one 64x64 tile per block ------------
  {
    int bid = blockIdx.x;
    int trow = bid % MTILES;
    int tcol = bid / MTILES;
    int row0 = trow * GBM;
    int col0 = tcol * GBN;
    int t = threadIdx.x;
    int lane = t & 63;
    int w = t >> 6;
    int wr = w >> 1;      // 0..1
    int wc = w & 1;       // 0..1
    int lhi = lane >> 4;  // 0..3
    int llo = lane & 15;

    f32x4 acc[2][2];
    #pragma unroll
    for (int m = 0; m < 2; ++m)
      #pragma unroll
      for (int n = 0; n < 2; ++n) acc[m][n] = (f32x4){0.f, 0.f, 0.f, 0.f};

    for (int k0 = 0; k0 < K_TOT; k0 += GBK) {
      // stage A: 64 rows x 64 k = 512 vec8, 2 per thread
      #pragma unroll
      for (int it = 0; it < 2; ++it) {
        int idx = t + it * 256;
        int r = idx >> 3;
        int kv = (idx & 7) * 8;
        int row = row0 + r;
        uint4 v = make_uint4(0, 0, 0, 0);
        if (row < N_NODES)
          v = *reinterpret_cast<const uint4*>(hcat + (size_t)row * K_TOT + k0 + kv);
        *reinterpret_cast<uint4*>(&As[r][kv]) = v;
      }
      // stage B: 64 cols x 64 k = 512 vec8, 2 per thread
      #pragma unroll
      for (int it = 0; it < 2; ++it) {
        int idx = t + it * 256;
        int c = idx >> 3;
        int kv = (idx & 7) * 8;
        uint4 v = *reinterpret_cast<const uint4*>(Wb + (size_t)(col0 + c) * K_TOT + k0 + kv);
        *reinterpret_cast<uint4*>(&Bs[c][kv]) = v;
      }
      __syncthreads();

      #pragma unroll
      for (int ks = 0; ks < 2; ++ks) {
        int ak = ks * 32 + lhi * 8;
        bf16x8 a[2], b[2];
        #pragma unroll
        for (int m = 0; m < 2; ++m)
          a[m] = *reinterpret_cast<const bf16x8*>(&As[wr * 32 + m * 16 + llo][ak]);
        #pragma unroll
        for (int n = 0; n < 2; ++n)
          b[n] = *reinterpret_cast<const bf16x8*>(&Bs[wc * 32 + n * 16 + llo][ak]);
        #pragma unroll
        for (int m = 0; m < 2; ++m)
          #pragma unroll
          for (int n = 0; n < 2; ++n)
            acc[m][n] = __builtin_amdgcn_mfma_f32_16x16x32_bf16(a[m], b[n], acc[m][n], 0, 0, 0);
      }
      __syncthreads();
    }

    #pragma unroll
    for (int m = 0; m < 2; ++m) {
      #pragma unroll
      for (int n = 0; n < 2; ++n) {
        int col = col0 + wc * 32 + n * 16 + llo;
        float bv = bias[col];
        #pragma unroll
        for (int r = 0; r < 4; ++r) {
          int orow = row0 + wr * 32 + m * 16 + lhi * 4 + r;
          if (orow < N_NODES)
            out[(size_t)orow * D + col] = acc[m][n][r] + bv;
        }
      }
    }
  }
}

extern "C" void kernel_launch(void* const* d_in, const int* in_sizes, int n_in,
                              void* d_out, int out_size, void* d_ws, size_t ws_size,
                              hipStream_t stream) {
  const float* feat = (const float*)d_in[0];   // [10000,256]
  const float* ew   = (const float*)d_in[1];   // [320000,1]
  const float* W    = (const float*)d_in[2];   // [256,512]
  const float* bias = (const float*)d_in[3];   // [256]
  const int*   src  = (const int*)d_in[4];     // [320000]
  const int*   dst  = (const int*)d_in[5];     // [320000]
  float* out = (float*)d_out;                  // [10000,256]

  // workspace layout
  char* ws = (char*)d_ws;
  unsigned short* hcat = (unsigned short*)ws;  ws += (size_t)N_NODES * K_TOT * sizeof(unsigned short); // 10.24 MB
  unsigned short* Wb   = (unsigned short*)ws;  ws += (size_t)D * K_TOT * sizeof(unsigned short);       // 0.26 MB
  int* cursor   = (int*)ws;                    ws += N_NODES * sizeof(int);
  int2* bucket  = (int2*)ws;                   ws += (size_t)N_NODES * CAP * sizeof(int2);             // 10.24 MB

  void* args[] = {
      (void*)&feat, (void*)&ew, (void*)&W, (void*)&bias,
      (void*)&src, (void*)&dst,
      (void*)&hcat, (void*)&Wb, (void*)&cursor, (void*)&bucket,
      (void*)&out};
  hipLaunchCooperativeKernel((void*)fused_kernel, dim3(GRID_BLKS), dim3(256),
                             args, 0, stream);
}

// Round 7
// 72.356 us; speedup vs baseline: 4.0729x; 4.0729x over previous
//
#include <hip/hip_runtime.h>
#include <hip/hip_bf16.h>

#define N_NODES 10000
#define N_EDGES 320000
#define D 256        // D_IN == D_OUT
#define K_TOT 512    // 2*D
#define CAP 128      // per-node bucket capacity (max Poisson(32) degree ~65)

typedef __attribute__((ext_vector_type(8))) short bf16x8;
typedef __attribute__((ext_vector_type(4))) float f32x4;

__device__ __forceinline__ float bf2f(unsigned short u) {
  return __uint_as_float(((unsigned int)u) << 16);
}
__device__ __forceinline__ unsigned short f2bf(float f) {
  unsigned int x = __float_as_uint(f);
  unsigned int r = (x + 0x7fffu + ((x >> 16) & 1u)) >> 16;   // RNE
  return (unsigned short)r;
}

// ---------------------------------------------------------------------------
// Pass 0: feat -> hcat[:,256:512] (bf16), W -> Wb (bf16), zero cursor.
// ---------------------------------------------------------------------------
#define FEAT_VECS (N_NODES * D / 8)     // 320000
#define W_VECS    (D * K_TOT / 8)       // 16384
#define CUR_VECS  (N_NODES / 4)         // 2500 (int4 zeroing)
__global__ __launch_bounds__(256) void tobf16_kernel(
    const float* __restrict__ feat, const float* __restrict__ W,
    unsigned short* __restrict__ hcat, unsigned short* __restrict__ Wb,
    int* __restrict__ cursor) {
  int gid = blockIdx.x * 256 + threadIdx.x;
  const float* srcp;
  unsigned short* dstp;
  if (gid < FEAT_VECS) {
    int row = gid >> 5;          // 32 vec8 per 256-row
    int v = gid & 31;
    srcp = feat + (size_t)row * D + v * 8;
    dstp = hcat + (size_t)row * K_TOT + D + v * 8;
  } else if (gid < FEAT_VECS + W_VECS) {
    int g = gid - FEAT_VECS;
    int row = g >> 6;            // 64 vec8 per 512-row
    int v = g & 63;
    srcp = W + (size_t)row * K_TOT + v * 8;
    dstp = Wb + (size_t)row * K_TOT + v * 8;
  } else if (gid < FEAT_VECS + W_VECS + CUR_VECS) {
    int g = gid - (FEAT_VECS + W_VECS);
    reinterpret_cast<int4*>(cursor)[g] = make_int4(0, 0, 0, 0);
    return;
  } else {
    return;
  }
  float4 a = reinterpret_cast<const float4*>(srcp)[0];
  float4 b = reinterpret_cast<const float4*>(srcp)[1];
  reinterpret_cast<ushort4*>(dstp)[0] =
      make_ushort4(f2bf(a.x), f2bf(a.y), f2bf(a.z), f2bf(a.w));
  reinterpret_cast<ushort4*>(dstp)[1] =
      make_ushort4(f2bf(b.x), f2bf(b.y), f2bf(b.z), f2bf(b.w));
}

// ---------------------------------------------------------------------------
// Pass 1: atomic-append edges into per-dst buckets. 2 edges per thread.
// ---------------------------------------------------------------------------
__global__ __launch_bounds__(256) void append_kernel(const int* __restrict__ src,
                                                     const int* __restrict__ dst,
                                                     const float* __restrict__ ew,
                                                     int* __restrict__ cursor,
                                                     int2* __restrict__ bucket) {
  int i = (blockIdx.x * 256 + threadIdx.x) * 2;
  if (i + 1 < N_EDGES) {
    int2 s2 = *reinterpret_cast<const int2*>(src + i);
    int2 d2 = *reinterpret_cast<const int2*>(dst + i);
    float2 w2 = *reinterpret_cast<const float2*>(ew + i);
    int pos0 = atomicAdd(&cursor[d2.x], 1);
    if (pos0 < CAP)
      bucket[(size_t)d2.x * CAP + pos0] = make_int2(s2.x, __float_as_int(w2.x));
    int pos1 = atomicAdd(&cursor[d2.y], 1);
    if (pos1 < CAP)
      bucket[(size_t)d2.y * CAP + pos1] = make_int2(s2.y, __float_as_int(w2.y));
  } else if (i < N_EDGES) {
    int d = dst[i];
    int pos = atomicAdd(&cursor[d], 1);
    if (pos < CAP)
      bucket[(size_t)d * CAP + pos] = make_int2(src[i], __float_as_int(ew[i]));
  }
}

// ---------------------------------------------------------------------------
// Pass 2: per-node mean-aggregation. One wave per node, lane = 4 channels.
// 8-edge unrolled gather pipeline (8 x 512B rows in flight per wave).
// ---------------------------------------------------------------------------
__global__ __launch_bounds__(256) void agg_kernel(const int* __restrict__ cursor,
                                                  const int2* __restrict__ bucket,
                                                  unsigned short* __restrict__ hcat) {
  int node = (blockIdx.x * 256 + threadIdx.x) >> 6;
  int lane = threadIdx.x & 63;
  if (node >= N_NODES) return;
  int cnt = cursor[node];
  int end = min(cnt, CAP);
  const int2* bk = bucket + (size_t)node * CAP;
  float acc0 = 0.f, acc1 = 0.f, acc2 = 0.f, acc3 = 0.f;
  int i = 0;
  for (; i + 8 <= end; i += 8) {
    int4 e01 = *reinterpret_cast<const int4*>(bk + i);
    int4 e23 = *reinterpret_cast<const int4*>(bk + i + 2);
    int4 e45 = *reinterpret_cast<const int4*>(bk + i + 4);
    int4 e67 = *reinterpret_cast<const int4*>(bk + i + 6);
    ushort4 v0 = *reinterpret_cast<const ushort4*>(hcat + (size_t)e01.x * K_TOT + D + lane * 4);
    ushort4 v1 = *reinterpret_cast<const ushort4*>(hcat + (size_t)e01.z * K_TOT + D + lane * 4);
    ushort4 v2 = *reinterpret_cast<const ushort4*>(hcat + (size_t)e23.x * K_TOT + D + lane * 4);
    ushort4 v3 = *reinterpret_cast<const ushort4*>(hcat + (size_t)e23.z * K_TOT + D + lane * 4);
    ushort4 v4 = *reinterpret_cast<const ushort4*>(hcat + (size_t)e45.x * K_TOT + D + lane * 4);
    ushort4 v5 = *reinterpret_cast<const ushort4*>(hcat + (size_t)e45.z * K_TOT + D + lane * 4);
    ushort4 v6 = *reinterpret_cast<const ushort4*>(hcat + (size_t)e67.x * K_TOT + D + lane * 4);
    ushort4 v7 = *reinterpret_cast<const ushort4*>(hcat + (size_t)e67.z * K_TOT + D + lane * 4);
    float w0 = __int_as_float(e01.y), w1 = __int_as_float(e01.w);
    float w2 = __int_as_float(e23.y), w3 = __int_as_float(e23.w);
    float w4 = __int_as_float(e45.y), w5 = __int_as_float(e45.w);
    float w6 = __int_as_float(e67.y), w7 = __int_as_float(e67.w);
    acc0 += bf2f(v0.x) * w0; acc1 += bf2f(v0.y) * w0; acc2 += bf2f(v0.z) * w0; acc3 += bf2f(v0.w) * w0;
    acc0 += bf2f(v1.x) * w1; acc1 += bf2f(v1.y) * w1; acc2 += bf2f(v1.z) * w1; acc3 += bf2f(v1.w) * w1;
    acc0 += bf2f(v2.x) * w2; acc1 += bf2f(v2.y) * w2; acc2 += bf2f(v2.z) * w2; acc3 += bf2f(v2.w) * w2;
    acc0 += bf2f(v3.x) * w3; acc1 += bf2f(v3.y) * w3; acc2 += bf2f(v3.z) * w3; acc3 += bf2f(v3.w) * w3;
    acc0 += bf2f(v4.x) * w4; acc1 += bf2f(v4.y) * w4; acc2 += bf2f(v4.z) * w4; acc3 += bf2f(v4.w) * w4;
    acc0 += bf2f(v5.x) * w5; acc1 += bf2f(v5.y) * w5; acc2 += bf2f(v5.z) * w5; acc3 += bf2f(v5.w) * w5;
    acc0 += bf2f(v6.x) * w6; acc1 += bf2f(v6.y) * w6; acc2 += bf2f(v6.z) * w6; acc3 += bf2f(v6.w) * w6;
    acc0 += bf2f(v7.x) * w7; acc1 += bf2f(v7.y) * w7; acc2 += bf2f(v7.z) * w7; acc3 += bf2f(v7.w) * w7;
  }
  for (; i < end; ++i) {
    int2 sw = bk[i];
    ushort4 v = *reinterpret_cast<const ushort4*>(hcat + (size_t)sw.x * K_TOT + D + lane * 4);
    float w = __int_as_float(sw.y);
    acc0 += bf2f(v.x) * w; acc1 += bf2f(v.y) * w; acc2 += bf2f(v.z) * w; acc3 += bf2f(v.w) * w;
  }
  float inv = 1.0f / fmaxf((float)cnt, 1.0f);
  ushort4 o = make_ushort4(f2bf(acc0 * inv), f2bf(acc1 * inv),
                           f2bf(acc2 * inv), f2bf(acc3 * inv));
  *reinterpret_cast<ushort4*>(hcat + (size_t)node * K_TOT + lane * 4) = o;
}

// ---------------------------------------------------------------------------
// Pass 3: MFMA GEMM. out[10000,256] = hcat[10000,512](bf16) @ Wb[256,512]^T + b
// Tile 64x64, BK=64, 256 threads = 4 waves (2x2), one tile per block.
// Grid 157x4 = 628 blocks: better CU balance than 316 (82% vs 62% tail util).
// ---------------------------------------------------------------------------
#define GBM 64
#define GBN 64
#define GBK 64
#define LPAD 72   // LDS row stride in bf16 elems (+8 pad: 2-way bank alias, free)

__global__ __launch_bounds__(256) void gemm_kernel(
    const unsigned short* __restrict__ hcat, const unsigned short* __restrict__ Wb,
    const float* __restrict__ bias, float* __restrict__ out) {
  __shared__ unsigned short As[GBM][LPAD];
  __shared__ unsigned short Bs[GBN][LPAD];

  int row0 = blockIdx.x * GBM;
  int col0 = blockIdx.y * GBN;
  int t = threadIdx.x;
  int lane = t & 63;
  int w = t >> 6;
  int wr = w >> 1;      // 0..1
  int wc = w & 1;       // 0..1
  int lhi = lane >> 4;  // 0..3
  int llo = lane & 15;

  f32x4 acc[2][2];
  #pragma unroll
  for (int m = 0; m < 2; ++m)
    #pragma unroll
    for (int n = 0; n < 2; ++n) acc[m][n] = (f32x4){0.f, 0.f, 0.f, 0.f};

  for (int k0 = 0; k0 < K_TOT; k0 += GBK) {
    // stage A: 64 rows x 64 k = 512 vec8, 2 per thread
    #pragma unroll
    for (int it = 0; it < 2; ++it) {
      int idx = t + it * 256;
      int r = idx >> 3;
      int kv = (idx & 7) * 8;
      int row = row0 + r;
      uint4 v = make_uint4(0, 0, 0, 0);
      if (row < N_NODES)
        v = *reinterpret_cast<const uint4*>(hcat + (size_t)row * K_TOT + k0 + kv);
      *reinterpret_cast<uint4*>(&As[r][kv]) = v;
    }
    // stage B: 64 cols x 64 k = 512 vec8, 2 per thread
    #pragma unroll
    for (int it = 0; it < 2; ++it) {
      int idx = t + it * 256;
      int c = idx >> 3;
      int kv = (idx & 7) * 8;
      uint4 v = *reinterpret_cast<const uint4*>(Wb + (size_t)(col0 + c) * K_TOT + k0 + kv);
      *reinterpret_cast<uint4*>(&Bs[c][kv]) = v;
    }
    __syncthreads();

    #pragma unroll
    for (int ks = 0; ks < 2; ++ks) {
      int ak = ks * 32 + lhi * 8;
      bf16x8 a[2], b[2];
      #pragma unroll
      for (int m = 0; m < 2; ++m)
        a[m] = *reinterpret_cast<const bf16x8*>(&As[wr * 32 + m * 16 + llo][ak]);
      #pragma unroll
      for (int n = 0; n < 2; ++n)
        b[n] = *reinterpret_cast<const bf16x8*>(&Bs[wc * 32 + n * 16 + llo][ak]);
      #pragma unroll
      for (int m = 0; m < 2; ++m)
        #pragma unroll
        for (int n = 0; n < 2; ++n)
          acc[m][n] = __builtin_amdgcn_mfma_f32_16x16x32_bf16(a[m], b[n], acc[m][n], 0, 0, 0);
    }
    __syncthreads();
  }

  #pragma unroll
  for (int m = 0; m < 2; ++m) {
    #pragma unroll
    for (int n = 0; n < 2; ++n) {
      int col = col0 + wc * 32 + n * 16 + llo;
      float bv = bias[col];
      #pragma unroll
      for (int r = 0; r < 4; ++r) {
        int orow = row0 + wr * 32 + m * 16 + lhi * 4 + r;
        if (orow < N_NODES)
          out[(size_t)orow * D + col] = acc[m][n][r] + bv;
      }
    }
  }
}

extern "C" void kernel_launch(void* const* d_in, const int* in_sizes, int n_in,
                              void* d_out, int out_size, void* d_ws, size_t ws_size,
                              hipStream_t stream) {
  const float* feat = (const float*)d_in[0];   // [10000,256]
  const float* ew   = (const float*)d_in[1];   // [320000,1]
  const float* W    = (const float*)d_in[2];   // [256,512]
  const float* bias = (const float*)d_in[3];   // [256]
  const int*   src  = (const int*)d_in[4];     // [320000]
  const int*   dst  = (const int*)d_in[5];     // [320000]
  float* out = (float*)d_out;                  // [10000,256]

  // workspace layout
  char* ws = (char*)d_ws;
  unsigned short* hcat = (unsigned short*)ws;  ws += (size_t)N_NODES * K_TOT * sizeof(unsigned short); // 10.24 MB
  unsigned short* Wb   = (unsigned short*)ws;  ws += (size_t)D * K_TOT * sizeof(unsigned short);       // 0.26 MB
  int* cursor   = (int*)ws;                    ws += N_NODES * sizeof(int);
  int2* bucket  = (int2*)ws;                   ws += (size_t)N_NODES * CAP * sizeof(int2);             // 10.24 MB

  tobf16_kernel<<<(FEAT_VECS + W_VECS + CUR_VECS + 255) / 256, 256, 0, stream>>>(
      feat, W, hcat, Wb, cursor);
  append_kernel<<<(N_EDGES / 2 + 255) / 256, 256, 0, stream>>>(src, dst, ew, cursor, bucket);
  agg_kernel<<<(N_NODES * 64 + 255) / 256, 256, 0, stream>>>(cursor, bucket, hcat);

  dim3 grid((N_NODES + GBM - 1) / GBM, D / GBN);
  gemm_kernel<<<grid, 256, 0, stream>>>(hcat, Wb, bias, out);
}